// Round 1
// baseline (523.768 us; speedup 1.0000x reference)
//
#include <hip/hip_runtime.h>

typedef unsigned short u16;
typedef unsigned int u32;
typedef _Float16 f16;
typedef f16 f16x2 __attribute__((ext_vector_type(2)));
typedef f16 f16x8 __attribute__((ext_vector_type(8)));
typedef __fp16 h16x2 __attribute__((ext_vector_type(2)));  // pkrtz return type
typedef float f32x4 __attribute__((ext_vector_type(4)));

#define M_DIM 8192
#define N_DIM 4096
#define K_DIM 4096

// ---------------------------------------------------------------------------
// Fused pre-pass (unchanged from baseline).
//  range 0: X fp32 -> fp16 (8 elems/thread, pkrtz)
//  range 1: repack 4-bit weights into splice-friendly nibble order
//  range 2: invmn[g][n] = { dup16(f16(1/scale)), dup16(f16(mn - 16*f16(1/scale))) }
// ---------------------------------------------------------------------------
#define XCVT_BLOCKS 16384  // M*K/8/256
#define W4_BLOCKS 8192     // N*(K/8)/256
#define IM_BLOCKS 1024     // 64*N/256

__global__ __launch_bounds__(256) void prep_kernel(
    const float4* __restrict__ x, uint4* __restrict__ xh,
    const int* __restrict__ packed, u32* __restrict__ w4,
    const float* __restrict__ mn, const float* __restrict__ scale,
    uint2* __restrict__ invmn) {
  int b = blockIdx.x;
  if (b < XCVT_BLOCKS) {
    int i = b * 256 + threadIdx.x;
    float4 a0 = x[2 * i], a1 = x[2 * i + 1];
    h16x2 h0 = __builtin_amdgcn_cvt_pkrtz(a0.x, a0.y);
    h16x2 h1 = __builtin_amdgcn_cvt_pkrtz(a0.z, a0.w);
    h16x2 h2 = __builtin_amdgcn_cvt_pkrtz(a1.x, a1.y);
    h16x2 h3 = __builtin_amdgcn_cvt_pkrtz(a1.z, a1.w);
    uint4 o;
    o.x = __builtin_bit_cast(u32, h0);
    o.y = __builtin_bit_cast(u32, h1);
    o.z = __builtin_bit_cast(u32, h2);
    o.w = __builtin_bit_cast(u32, h3);
    xh[i] = o;
  } else if (b < XCVT_BLOCKS + W4_BLOCKS) {
    int idx = (b - XCVT_BLOCKS) * 256 + threadIdx.x;  // n*512 + w
    int n = idx >> 9, w = idx & 511;
    int g = w >> 3;
    int jb = (w & 7) << 3;                      // 0..56; <32 = hi nibbles
    int sh = (jb < 32) ? 4 : 0;
    const int* p = packed + n * 2048 + g * 32 + (jb & 31);
    u32 out = 0;
#pragma unroll
    for (int t = 0; t < 8; t++) {
      u32 nib = ((u32)p[t] >> sh) & 0xFu;
      int pos = ((t & 1) ? 16 : 0) + ((t >> 1) << 2);
      out |= nib << pos;
    }
    w4[idx] = out;
  } else {
    int idx = (b - XCVT_BLOCKS - W4_BLOCKS) * 256 + threadIdx.x;  // g*4096+n
    int n = idx & 4095, g = idx >> 12;
    float sc = scale[n * 64 + g];
    float m = mn[n * 64 + g];
    f16 invh = (f16)(1.0f / sc);
    f16 mnh = (f16)(m - 16.0f * (float)invh);
    u32 ib = (u32)__builtin_bit_cast(u16, invh);
    u32 mb = (u32)__builtin_bit_cast(u16, mnh);
    uint2 o;
    o.x = ib | (ib << 16);
    o.y = mb | (mb << 16);
    invmn[idx] = o;
  }
}

// ---------------------------------------------------------------------------
// GEMM: C[M][N] = Xh[M][K](fp16) * dequant(B4)[N][K]^T + bias
// Block 256x128 tile, 4 waves in 2x2, wave-tile 128x64.
// This round:
//  * LDS double-buffered across K-steps; stage(kk+1) issued BEFORE compute(kk),
//    ONE __syncthreads per K-step (its vmcnt(0) drain is the pipeline wait).
//    Correctness: buf^1's readers finished before the barrier of step kk-1
//    (lgkm waits precede MFMA use), so overwrite at step kk is safe; buf's
//    data was drained at the previous barrier.
//  * A-source pre-swizzle to kill the 8-way bank conflict on af[] ds_read_b128:
//    LDS dest stays linear (global_load_lds constraint); the SOURCE 16B-chunk
//    is permuted with key = row bits [2:1] (row&3 is NOT enough at 64B rows):
//      store: chunk_g = (lane&3) ^ ((lane>>3)&3)
//      read : chunk   = lq ^ ((lr>>1)&3)
//    -> every bank-group gets exactly 2 lanes (2-way = free).
//  * {inv,mn} per-group loads register-double-buffered (hide L2 latency).
// Occupancy: 72 KB LDS x 2 blocks = 144 <= 160 KB; acc AGPRs (128) + VGPRs
// already cap at 2 waves/SIMD, so the LDS growth is free.
// ---------------------------------------------------------------------------
__device__ __forceinline__ void gload_lds16(const void* g, void* l) {
  __builtin_amdgcn_global_load_lds(
      (const __attribute__((address_space(1))) void*)g,
      (__attribute__((address_space(3))) void*)l, 16, 0, 0);
}

__global__ __launch_bounds__(256, 2) void gemm4_kernel(
    const u16* __restrict__ A,     // fp16 [8192][4096]
    const u32* __restrict__ B4,    // [4096][512] splice-ordered nibble dwords
    const uint2* __restrict__ IM,  // [64][4096] {inv2, mn2}
    const float* __restrict__ bias, float* __restrict__ C) {
  __shared__ alignas(16) u16 As[2][2][256 * 32];  // [dbuf][k32][row][32] 64 KB
  __shared__ alignas(16) u32 Bs[2][2][128 * 4];   // [dbuf][k32][row][4]   8 KB

  const int tid = threadIdx.x;
  const int wave = tid >> 6, lane = tid & 63;
  const int lr = lane & 15, lq = lane >> 4;
  const int bn = blockIdx.x & 31, bm = blockIdx.x >> 5;
  const int m0 = bm << 8, n0 = bn << 7;
  const int wm = (wave & 1) << 7, wn = (wave >> 1) << 6;

  // A staging: wave covers rows 64*wave..+63 over 4 passes (c), 2 subtiles (s).
  // Source chunk permuted so linear LDS dest ends up bank-swizzled.
  const int chunkg = (lane & 3) ^ ((lane >> 3) & 3);
  const u16* pA =
      A + (size_t)(m0 + (wave << 6) + (lane >> 2)) * K_DIM + (chunkg << 3);
  char* dstA = (char*)(&As[0][0][0]) + wave * 4096 + lane * 16;
  // B staging: 1 pass/wave: h = wave>>1, row = 64*(wave&1)+lane (dword units)
  const u32* pB = B4 + (size_t)(n0 + ((wave & 1) << 6) + lane) * 512 +
                  ((wave >> 1) << 2);
  char* dstB = (char*)(&Bs[0][0][0]) + wave * 1024 + lane * 16;
  const uint2* pI = IM + n0 + wn + lr;
  const int aswz = (lq ^ ((lr >> 1) & 3)) << 4;  // read-side swizzled chunk

  f32x4 acc[8][4] = {};

  // ---- prologue: stage kk=0 into buf 0; preload im for kk=0 ----
#pragma unroll
  for (int s = 0; s < 2; s++)
#pragma unroll
    for (int c = 0; c < 4; c++)
      gload_lds16(pA + s * 32 + (size_t)c * 16 * K_DIM,
                  dstA + s * 16384 + c * 1024);
  gload_lds16(pB, dstB);
  uint2 imc[4];
#pragma unroll
  for (int j = 0; j < 4; j++) imc[j] = pI[j * 16];
  __syncthreads();  // vmcnt(0) drain: buf0 + imc ready

#pragma unroll 2
  for (int kk = 0; kk < 64; ++kk) {  // k0 = kk*64; group g == kk
    const int buf = kk & 1;
    uint2 imn[4];
    if (kk < 63) {
      const int nb = buf ^ 1;
      // issue next tile's stage FIRST — latency hides under compute(buf)
#pragma unroll
      for (int s = 0; s < 2; s++)
#pragma unroll
        for (int c = 0; c < 4; c++)
          gload_lds16(pA + (kk + 1) * 64 + s * 32 + (size_t)c * 16 * K_DIM,
                      dstA + nb * 32768 + s * 16384 + c * 1024);
      gload_lds16(pB + (kk + 1) * 8, dstB + nb * 4096);
#pragma unroll
      for (int j = 0; j < 4; j++) imn[j] = pI[(kk + 1) * 4096 + j * 16];
    }

    const char* aB = (const char*)(&As[0][0][0]) + buf * 32768;
    const char* bB = (const char*)(&Bs[0][0][0]) + buf * 4096;
#pragma unroll
    for (int s = 0; s < 2; s++) {
      f16x8 af[8];
#pragma unroll
      for (int i = 0; i < 8; i++)
        af[i] = *(const f16x8*)(aB + s * 16384 + (wm + i * 16 + lr) * 64 + aswz);
      u32 braw[4];
#pragma unroll
      for (int j = 0; j < 4; j++)
        braw[j] =
            *(const u32*)(bB + s * 2048 + (((wn + j * 16 + lr) << 2) + lq) * 4);

      f16x8 bf[4];
#pragma unroll
      for (int j = 0; j < 4; j++) {
        u32 d = braw[j];
        u32 q0 = ((d << 6) & 0x03C003C0u) | 0x4C004C00u;  // fp16(16+v) pairs
        u32 q1 = ((d << 2) & 0x03C003C0u) | 0x4C004C00u;
        u32 q2 = ((d >> 2) & 0x03C003C0u) | 0x4C004C00u;
        u32 q3 = ((d >> 6) & 0x03C003C0u) | 0x4C004C00u;
        f16x2 inv2 = __builtin_bit_cast(f16x2, imc[j].x);
        f16x2 mn2 = __builtin_bit_cast(f16x2, imc[j].y);
        f16x2 w0 = __builtin_elementwise_fma(__builtin_bit_cast(f16x2, q0), inv2, mn2);
        f16x2 w1 = __builtin_elementwise_fma(__builtin_bit_cast(f16x2, q1), inv2, mn2);
        f16x2 w2 = __builtin_elementwise_fma(__builtin_bit_cast(f16x2, q2), inv2, mn2);
        f16x2 w3 = __builtin_elementwise_fma(__builtin_bit_cast(f16x2, q3), inv2, mn2);
        union {
          f16x8 v;
          u32 d[4];
        } u;
        u.d[0] = __builtin_bit_cast(u32, w0);
        u.d[1] = __builtin_bit_cast(u32, w1);
        u.d[2] = __builtin_bit_cast(u32, w2);
        u.d[3] = __builtin_bit_cast(u32, w3);
        bf[j] = u.v;
      }
#pragma unroll
      for (int i = 0; i < 8; i++)
#pragma unroll
        for (int j = 0; j < 4; j++)
          acc[i][j] = __builtin_amdgcn_mfma_f32_16x16x32_f16(af[i], bf[j],
                                                             acc[i][j], 0, 0, 0);
    }
    __syncthreads();  // drains vmcnt(0): stage(kk+1)+imn landed; buf reusable
    if (kk < 63) {
#pragma unroll
      for (int j = 0; j < 4; j++) imc[j] = imn[j];
    }
  }

  // Epilogue: C/D layout col=lane&15, row=(lane>>4)*4+t (unchanged, verified)
#pragma unroll
  for (int j = 0; j < 4; j++) {
    int n = n0 + wn + j * 16 + lr;
    float bv = bias[n];
#pragma unroll
    for (int i = 0; i < 8; i++) {
      int mb = m0 + wm + i * 16 + (lq << 2);
#pragma unroll
      for (int t = 0; t < 4; t++)
        C[(size_t)(mb + t) * N_DIM + n] = acc[i][j][t] + bv;
    }
  }
}

// ---------------- fallback (only if ws too small): naive tiled fp32 --------
__global__ __launch_bounds__(256) void fallback_gemm(
    const float* __restrict__ x, const int* __restrict__ packed,
    const float* __restrict__ mn, const float* __restrict__ scale,
    const float* __restrict__ bias, float* __restrict__ out) {
  __shared__ float As[16][17];
  __shared__ float Bs[16][17];
  int tx = threadIdx.x & 15, ty = threadIdx.x >> 4;
  int m = blockIdx.y * 16 + ty;
  int n = blockIdx.x * 16 + tx;
  float acc = 0.f;
  for (int k0 = 0; k0 < K_DIM; k0 += 16) {
    As[ty][tx] = x[(size_t)m * K_DIM + k0 + tx];
    int nn = blockIdx.x * 16 + ty;
    int k = k0 + tx;
    int g = k >> 6, pos = k & 63;
    int p = packed[nn * 2048 + g * 32 + (pos & 31)];
    int v = (pos < 32) ? ((p >> 4) & 0xF) : (p & 0xF);
    Bs[ty][tx] = (float)v / scale[nn * 64 + g] + mn[nn * 64 + g];
    __syncthreads();
#pragma unroll
    for (int kk = 0; kk < 16; kk++) acc += As[ty][kk] * Bs[tx][kk];
    __syncthreads();
  }
  out[(size_t)m * N_DIM + n] = acc + bias[n];
}

extern "C" void kernel_launch(void* const* d_in, const int* in_sizes, int n_in,
                              void* d_out, int out_size, void* d_ws,
                              size_t ws_size, hipStream_t stream) {
  const float* x = (const float*)d_in[0];      // [4,2048,4096] fp32
  const int* packed = (const int*)d_in[1];     // [4096,64,32] int32
  const float* mn = (const float*)d_in[2];     // [4096,64,1]
  const float* scale = (const float*)d_in[3];  // [4096,64,1]
  const float* bias = (const float*)d_in[4];   // [4096]
  float* out = (float*)d_out;                  // [8192,4096]

  const size_t offW4 = (size_t)M_DIM * K_DIM * 2;          // Xh: 64 MB
  const size_t offIM = offW4 + (size_t)N_DIM * K_DIM / 2;  // W4: 8 MB
  const size_t need = offIM + (size_t)64 * N_DIM * 8;      // IM: 2 MB

  if (ws_size >= need) {
    u16* Xh = (u16*)d_ws;
    u32* W4 = (u32*)((char*)d_ws + offW4);
    uint2* IMp = (uint2*)((char*)d_ws + offIM);
    prep_kernel<<<XCVT_BLOCKS + W4_BLOCKS + IM_BLOCKS, 256, 0, stream>>>(
        (const float4*)x, (uint4*)Xh, packed, W4, mn, scale, IMp);
    gemm4_kernel<<<(M_DIM / 256) * (N_DIM / 128), 256, 0, stream>>>(
        Xh, W4, IMp, bias, out);
  } else {
    dim3 grid(N_DIM / 16, M_DIM / 16);
    fallback_gemm<<<grid, 256, 0, stream>>>(x, packed, mn, scale, bias, out);
  }
}